// Round 1
// baseline (314.468 us; speedup 1.0000x reference)
//
#include <hip/hip_runtime.h>
#include <hip/hip_bf16.h>
#include <stdint.h>

#define DEV static __device__ __forceinline__

typedef __attribute__((ext_vector_type(8))) __bf16 bf16x8;
typedef __attribute__((ext_vector_type(4))) float f32x4;

// B=2, T=2048, C=1024, NH=16, HS=64
#define BB 2
#define TT 2048
#define CC 1024
#define NHH 16
#define HSS 64
#define BT 4096
#define N3 3072

DEV unsigned short f2bf(float f) {
  union { float f; uint32_t u; } v; v.f = f;
  uint32_t r = v.u + 0x7FFFu + ((v.u >> 16) & 1u);
  return (unsigned short)(r >> 16);
}

typedef const __attribute__((address_space(1))) unsigned int* gas_t;
typedef __attribute__((address_space(3))) unsigned int* las_t;

DEV void glds16(const void* g, void* l) {
  __builtin_amdgcn_global_load_lds((gas_t)g, (las_t)l, 16, 0, 0);
}

DEV f32x4 mfma16(bf16x8 a, bf16x8 b, f32x4 c) {
  return __builtin_amdgcn_mfma_f32_16x16x32_bf16(a, b, c, 0, 0, 0);
}

DEV bf16x8 ld8(const unsigned short* p) { return *(const bf16x8*)p; }

// ---------- fp32 -> bf16 convert (vectorized) ----------
__global__ void k_conv(const float* __restrict__ in, unsigned short* __restrict__ out, int n4) {
  int i = blockIdx.x * blockDim.x + threadIdx.x;
  int stride = gridDim.x * blockDim.x;
  for (; i < n4; i += stride) {
    float4 v = ((const float4*)in)[i];
    ushort4 o;
    o.x = f2bf(v.x); o.y = f2bf(v.y); o.z = f2bf(v.z); o.w = f2bf(v.w);
    ((ushort4*)out)[i] = o;
  }
}

// ---------- transpose+convert: in [K][N] f32 -> out [N][K] bf16 ----------
__global__ void k_transp(const float* __restrict__ in, unsigned short* __restrict__ out,
                         int K, int N) {
  __shared__ float tile[32][33];
  int n0 = blockIdx.x * 32, k0 = blockIdx.y * 32;
  int tx = threadIdx.x, ty = threadIdx.y;  // (32,8)
  for (int r = ty; r < 32; r += 8)
    tile[r][tx] = in[(size_t)(k0 + r) * N + n0 + tx];
  __syncthreads();
  for (int r = ty; r < 32; r += 8)
    out[(size_t)(n0 + r) * K + k0 + tx] = f2bf(tile[tx][r]);
}

// ---------- m97-structure GEMM: A[M][K] bf16, Bt[N][K] bf16, bias f32[N] ----------
// 128x128 tile, BK=32, 4 waves (2x2), 16x16x32 bf16 MFMA, global_load_lds width 16.
template <int OUT_BF16>
__global__ __launch_bounds__(256) void k_gemm(const unsigned short* __restrict__ A,
                                              const unsigned short* __restrict__ Bt,
                                              const float* __restrict__ bias,
                                              void* __restrict__ Cout,
                                              int M, int N, int K) {
  __shared__ __align__(16) unsigned short As[128 * 32];
  __shared__ __align__(16) unsigned short Bs[128 * 32];
  const int t = threadIdx.x;
  const int wave = t >> 6, l = t & 63, lr = l & 15, lg = l >> 4;
  const int m0 = blockIdx.y * 128, n0 = blockIdx.x * 128;
  const int wm = wave >> 1, wn = wave & 1;

  f32x4 acc[4][4] = {};

  // staging map: thread t -> row t/4 (call0) / row 64+t/4 (call1), 16B chunk (t&3)
  const unsigned short* gA = A + (size_t)(m0 + (t >> 2)) * K + (t & 3) * 8;
  const unsigned short* gB = Bt + (size_t)(n0 + (t >> 2)) * K + (t & 3) * 8;
  char* lA = (char*)As + wave * 1024;
  char* lB = (char*)Bs + wave * 1024;
  const size_t rstep = (size_t)64 * K;

  for (int k0 = 0; k0 < K; k0 += 32) {
    glds16(gA + k0, lA);
    glds16(gA + rstep + k0, lA + 4096);
    glds16(gB + k0, lB);
    glds16(gB + rstep + k0, lB + 4096);
    __syncthreads();
    bf16x8 av[4], bv[4];
#pragma unroll
    for (int i = 0; i < 4; i++) {
      av[i] = ld8(As + (wm * 64 + i * 16 + lr) * 32 + lg * 8);
      bv[i] = ld8(Bs + (wn * 64 + i * 16 + lr) * 32 + lg * 8);
    }
#pragma unroll
    for (int i = 0; i < 4; i++)
#pragma unroll
      for (int j = 0; j < 4; j++)
        acc[i][j] = mfma16(av[i], bv[j], acc[i][j]);
    __syncthreads();
  }

#pragma unroll
  for (int j2 = 0; j2 < 4; j2++) {
    int col = n0 + wn * 64 + j2 * 16 + lr;
    float bv_ = bias[col];
#pragma unroll
    for (int i = 0; i < 4; i++) {
      int row = m0 + wm * 64 + i * 16 + lg * 4;
#pragma unroll
      for (int r = 0; r < 4; r++) {
        float v = acc[i][j2][r] + bv_;
        if (OUT_BF16)
          ((unsigned short*)Cout)[(size_t)(row + r) * N + col] = f2bf(v);
        else
          ((float*)Cout)[(size_t)(row + r) * N + col] = v;
      }
    }
  }
}

// ---------- per-head V transpose: qkv[b][t][2048+h*64+d] -> vt[bh][d][t] ----------
__global__ void k_vt(const unsigned short* __restrict__ qkv, unsigned short* __restrict__ vt) {
  __shared__ unsigned short tile[64][65];
  int bh = blockIdx.y, t0 = blockIdx.x * 64;
  int b = bh >> 4, h = bh & 15;
  int tx = threadIdx.x, ty = threadIdx.y;  // (64,4)
  const unsigned short* src = qkv + (size_t)(b * TT + t0) * N3 + 2 * CC + h * HSS;
  for (int r = ty; r < 64; r += 4)
    tile[r][tx] = src[(size_t)r * N3 + tx];
  __syncthreads();
  unsigned short* dst = vt + (size_t)bh * HSS * TT + t0;
  for (int r = ty; r < 64; r += 4)
    dst[(size_t)r * TT + tx] = tile[tx][r];
}

// ---------- flash attention: 1 wave per 16 q rows, kv tiles of 32 ----------
// S^T = mfma(K, Q)  (lane: col q=lr, row kv=4*lg+j); softmax via shfl_xor reduce;
// P -> bf16 -> LDS bounce -> PV A-frag; PV B-frag from vt (K-contiguous).
__global__ __launch_bounds__(256) void k_attn(const unsigned short* __restrict__ qkv,
                                              const unsigned short* __restrict__ vt,
                                              unsigned short* __restrict__ y) {
  __shared__ __align__(16) unsigned short ldsP[4 * 512];  // per wave: 16 q x 32 kv
  const int t = threadIdx.x;
  const int wave = t >> 6, l = t & 63, lr = l & 15, lg = l >> 4;
  const int bh = blockIdx.y, b = bh >> 4, h = bh & 15;
  const int q0 = blockIdx.x * 64 + wave * 16;
  const float cexp = 0.18033688011112042f;  // (1/8) * log2(e)

  const unsigned short* qbase = qkv + (size_t)(b * TT + q0 + lr) * N3 + h * HSS;
  bf16x8 qf0 = ld8(qbase + lg * 8);
  bf16x8 qf1 = ld8(qbase + 32 + lg * 8);

  const unsigned short* kbase = qkv + (size_t)(b * TT) * N3 + CC + h * HSS;
  const unsigned short* vbase = vt + (size_t)bh * HSS * TT;

  float m_s = -INFINITY, l_s = 0.f;
  f32x4 o[4] = {};
  unsigned short* myP = ldsP + wave * 512 + lr * 32;

  const int q = q0 + lr;
  const int kv_last = q0 + 15;
  for (int kv0 = 0; kv0 <= kv_last; kv0 += 32) {
    const unsigned short* kp = kbase + (size_t)(kv0 + lr) * N3 + lg * 8;
    bf16x8 kf00 = ld8(kp);
    bf16x8 kf01 = ld8(kp + 32);
    bf16x8 kf10 = ld8(kp + 16 * N3);
    bf16x8 kf11 = ld8(kp + 16 * N3 + 32);
    f32x4 s0 = {0.f, 0.f, 0.f, 0.f}, s1 = {0.f, 0.f, 0.f, 0.f};
    s0 = mfma16(kf00, qf0, s0);
    s0 = mfma16(kf01, qf1, s0);
    s1 = mfma16(kf10, qf0, s1);
    s1 = mfma16(kf11, qf1, s1);

    float tmax = -INFINITY;
#pragma unroll
    for (int j = 0; j < 4; j++) {
      int kva = kv0 + 4 * lg + j;
      float va = (kva <= q) ? s0[j] : -INFINITY;
      float vb = (kva + 16 <= q) ? s1[j] : -INFINITY;
      s0[j] = va; s1[j] = vb;
      tmax = fmaxf(tmax, fmaxf(va, vb));
    }
    tmax = fmaxf(tmax, __shfl_xor(tmax, 16));
    tmax = fmaxf(tmax, __shfl_xor(tmax, 32));
    float m_new = fmaxf(m_s, tmax);
    float alpha = __builtin_amdgcn_exp2f((m_s - m_new) * cexp);

    float p0[4], p1[4];
    float tsum = 0.f;
#pragma unroll
    for (int j = 0; j < 4; j++) {
      p0[j] = __builtin_amdgcn_exp2f((s0[j] - m_new) * cexp);
      p1[j] = __builtin_amdgcn_exp2f((s1[j] - m_new) * cexp);
      tsum += p0[j] + p1[j];
    }
    tsum += __shfl_xor(tsum, 16);
    tsum += __shfl_xor(tsum, 32);
    m_s = m_new;
    l_s = l_s * alpha + tsum;

    // P^T -> ldsP[q=lr][kv] as bf16
    ushort4 w0, w1;
    w0.x = f2bf(p0[0]); w0.y = f2bf(p0[1]); w0.z = f2bf(p0[2]); w0.w = f2bf(p0[3]);
    w1.x = f2bf(p1[0]); w1.y = f2bf(p1[1]); w1.z = f2bf(p1[2]); w1.w = f2bf(p1[3]);
    *(ushort4*)(myP + 4 * lg) = w0;        // kv = 4*lg+j
    *(ushort4*)(myP + 16 + 4 * lg) = w1;   // kv = 16+4*lg+j
    asm volatile("s_waitcnt lgkmcnt(0)" ::: "memory");
    __builtin_amdgcn_sched_barrier(0);
    bf16x8 pa = ld8(ldsP + wave * 512 + lr * 32 + lg * 8);  // A-frag: q=lr, kv=8*lg+j

    float ar[4];
#pragma unroll
    for (int j = 0; j < 4; j++) ar[j] = __shfl(alpha, 4 * lg + j);
#pragma unroll
    for (int nt = 0; nt < 4; nt++) {
#pragma unroll
      for (int j = 0; j < 4; j++) o[nt][j] *= ar[j];
      bf16x8 vf = ld8(vbase + (size_t)(nt * 16 + lr) * TT + kv0 + lg * 8);
      o[nt] = mfma16(pa, vf, o[nt]);
    }
  }

  float lrow[4];
#pragma unroll
  for (int j = 0; j < 4; j++) lrow[j] = __shfl(l_s, 4 * lg + j);
  unsigned short* yrow = y + (size_t)(b * TT + q0 + 4 * lg) * CC + h * HSS + lr;
#pragma unroll
  for (int nt = 0; nt < 4; nt++)
#pragma unroll
    for (int j = 0; j < 4; j++)
      yrow[(size_t)j * CC + nt * 16] = f2bf(o[nt][j] / lrow[j]);
}

extern "C" void kernel_launch(void* const* d_in, const int* in_sizes, int n_in,
                              void* d_out, int out_size, void* d_ws, size_t ws_size,
                              hipStream_t stream) {
  const float* x = (const float*)d_in[0];
  const float* W_attn = (const float*)d_in[1];
  const float* b_attn = (const float*)d_in[2];
  const float* W_proj = (const float*)d_in[3];
  const float* b_proj = (const float*)d_in[4];

  char* ws = (char*)d_ws;
  unsigned short* xb   = (unsigned short*)(ws);                       // 8 MB
  unsigned short* wabt = (unsigned short*)(ws + 8388608);             // 6 MB  [3072][1024]
  unsigned short* wpbt = (unsigned short*)(ws + 14680064);            // 2 MB  [1024][1024]
  unsigned short* qkvb = (unsigned short*)(ws + 16777216);            // 24 MB [4096][3072]
  unsigned short* vt   = (unsigned short*)(ws + 41943040);            // 8 MB  [32][64][2048]
  unsigned short* yb   = (unsigned short*)(ws + 50331648);            // 8 MB  [4096][1024]

  // 1) convert x
  k_conv<<<2048, 256, 0, stream>>>(x, xb, BT * CC / 4);
  // 2) transpose weights
  k_transp<<<dim3(N3 / 32, CC / 32), dim3(32, 8), 0, stream>>>(W_attn, wabt, CC, N3);
  k_transp<<<dim3(CC / 32, CC / 32), dim3(32, 8), 0, stream>>>(W_proj, wpbt, CC, CC);
  // 3) qkv = x @ W_attn + b_attn  (bf16 out)
  k_gemm<1><<<dim3(N3 / 128, BT / 128), 256, 0, stream>>>(xb, wabt, b_attn, qkvb, BT, N3, CC);
  // 4) vt
  k_vt<<<dim3(TT / 64, BB * NHH), dim3(64, 4), 0, stream>>>(qkvb, vt);
  // 5) attention -> yb
  k_attn<<<dim3(TT / 64, BB * NHH), 256, 0, stream>>>(qkvb, vt, yb);
  // 6) out = yb @ W_proj + b_proj (fp32 out)
  k_gemm<0><<<dim3(CC / 128, BT / 128), 256, 0, stream>>>(yb, wpbt, b_proj, d_out, BT, CC, CC);
}

// Round 2
// 162.926 us; speedup vs baseline: 1.9301x; 1.9301x over previous
//
#include <hip/hip_runtime.h>
#include <hip/hip_bf16.h>
#include <stdint.h>

#define DEV static __device__ __forceinline__

typedef __attribute__((ext_vector_type(8))) __bf16 bf16x8;
typedef __attribute__((ext_vector_type(4))) float f32x4;

// B=2, T=2048, C=1024, NH=16, HS=64
#define BB 2
#define TT 2048
#define CC 1024
#define NHH 16
#define HSS 64
#define BT 4096
#define N3 3072

DEV unsigned short f2bf(float f) {
  union { float f; uint32_t u; } v; v.f = f;
  uint32_t r = v.u + 0x7FFFu + ((v.u >> 16) & 1u);
  return (unsigned short)(r >> 16);
}

typedef const __attribute__((address_space(1))) unsigned int* gas_t;
typedef __attribute__((address_space(3))) unsigned int* las_t;

DEV void glds16(const void* g, void* l) {
  __builtin_amdgcn_global_load_lds((gas_t)g, (las_t)l, 16, 0, 0);
}

DEV f32x4 mfma16(bf16x8 a, bf16x8 b, f32x4 c) {
  return __builtin_amdgcn_mfma_f32_16x16x32_bf16(a, b, c, 0, 0, 0);
}

DEV bf16x8 ld8(const unsigned short* p) { return *(const bf16x8*)p; }

// ---------- fp32 -> bf16 convert (vectorized) ----------
__global__ void k_conv(const float* __restrict__ in, unsigned short* __restrict__ out, int n4) {
  int i = blockIdx.x * blockDim.x + threadIdx.x;
  int stride = gridDim.x * blockDim.x;
  for (; i < n4; i += stride) {
    float4 v = ((const float4*)in)[i];
    ushort4 o;
    o.x = f2bf(v.x); o.y = f2bf(v.y); o.z = f2bf(v.z); o.w = f2bf(v.w);
    ((ushort4*)out)[i] = o;
  }
}

// ---------- transpose+convert: in [K][N] f32 -> out [N][K] bf16 ----------
__global__ void k_transp(const float* __restrict__ in, unsigned short* __restrict__ out,
                         int K, int N) {
  __shared__ float tile[32][33];
  int n0 = blockIdx.x * 32, k0 = blockIdx.y * 32;
  int tx = threadIdx.x, ty = threadIdx.y;  // (32,8)
  for (int r = ty; r < 32; r += 8)
    tile[r][tx] = in[(size_t)(k0 + r) * N + n0 + tx];
  __syncthreads();
  for (int r = ty; r < 32; r += 8)
    out[(size_t)(n0 + r) * K + k0 + tx] = f2bf(tile[tx][r]);
}

// ---------- m97-structure GEMM: A[M][K] bf16, Bt[N][K] bf16, bias f32[N] ----------
template <int OUT_BF16>
__global__ __launch_bounds__(256) void k_gemm(const unsigned short* __restrict__ A,
                                              const unsigned short* __restrict__ Bt,
                                              const float* __restrict__ bias,
                                              void* __restrict__ Cout,
                                              int M, int N, int K) {
  __shared__ __align__(16) unsigned short As[128 * 32];
  __shared__ __align__(16) unsigned short Bs[128 * 32];
  const int t = threadIdx.x;
  const int wave = t >> 6, l = t & 63, lr = l & 15, lg = l >> 4;
  const int m0 = blockIdx.y * 128, n0 = blockIdx.x * 128;
  const int wm = wave >> 1, wn = wave & 1;

  f32x4 acc[4][4] = {};

  const unsigned short* gA = A + (size_t)(m0 + (t >> 2)) * K + (t & 3) * 8;
  const unsigned short* gB = Bt + (size_t)(n0 + (t >> 2)) * K + (t & 3) * 8;
  char* lA = (char*)As + wave * 1024;
  char* lB = (char*)Bs + wave * 1024;
  const size_t rstep = (size_t)64 * K;

  for (int k0 = 0; k0 < K; k0 += 32) {
    glds16(gA + k0, lA);
    glds16(gA + rstep + k0, lA + 4096);
    glds16(gB + k0, lB);
    glds16(gB + rstep + k0, lB + 4096);
    __syncthreads();
    bf16x8 av[4], bv[4];
#pragma unroll
    for (int i = 0; i < 4; i++) {
      av[i] = ld8(As + (wm * 64 + i * 16 + lr) * 32 + lg * 8);
      bv[i] = ld8(Bs + (wn * 64 + i * 16 + lr) * 32 + lg * 8);
    }
#pragma unroll
    for (int i = 0; i < 4; i++)
#pragma unroll
      for (int j = 0; j < 4; j++)
        acc[i][j] = mfma16(av[i], bv[j], acc[i][j]);
    __syncthreads();
  }

#pragma unroll
  for (int j2 = 0; j2 < 4; j2++) {
    int col = n0 + wn * 64 + j2 * 16 + lr;
    float bv_ = bias[col];
#pragma unroll
    for (int i = 0; i < 4; i++) {
      int row = m0 + wm * 64 + i * 16 + lg * 4;
#pragma unroll
      for (int r = 0; r < 4; r++) {
        float v = acc[i][j2][r] + bv_;
        if (OUT_BF16)
          ((unsigned short*)Cout)[(size_t)(row + r) * N + col] = f2bf(v);
        else
          ((float*)Cout)[(size_t)(row + r) * N + col] = v;
      }
    }
  }
}

// ---------- per-head V transpose: qkv[b][t][2048+h*64+d] -> vt[bh][d][t] ----------
__global__ void k_vt(const unsigned short* __restrict__ qkv, unsigned short* __restrict__ vt) {
  __shared__ unsigned short tile[64][65];
  int bh = blockIdx.y, t0 = blockIdx.x * 64;
  int b = bh >> 4, h = bh & 15;
  int tx = threadIdx.x, ty = threadIdx.y;  // (64,4)
  const unsigned short* src = qkv + (size_t)(b * TT + t0) * N3 + 2 * CC + h * HSS;
  for (int r = ty; r < 64; r += 4)
    tile[r][tx] = src[(size_t)r * N3 + tx];
  __syncthreads();
  unsigned short* dst = vt + (size_t)bh * HSS * TT + t0;
  for (int r = ty; r < 64; r += 4)
    dst[(size_t)r * TT + tx] = tile[tx][r];
}

// ---------- flash attention, LDS-staged K/V, double-buffered ----------
// Block: 4 waves, q-tile 64 (16 q/wave), kv tiles of 64.
// K tile [64 kv][64 d], V tile [64 d][64 kv] (from vt), both XOR-swizzled
// ((row&7)<<4) via pre-swizzled global source + linear LDS dest (glds16).
__global__ __launch_bounds__(256) void k_attn(const unsigned short* __restrict__ qkv,
                                              const unsigned short* __restrict__ vt,
                                              unsigned short* __restrict__ y) {
  __shared__ __align__(16) unsigned short Ks[2][64 * 64];
  __shared__ __align__(16) unsigned short Vs[2][64 * 64];
  __shared__ __align__(16) unsigned short Ps[4][16 * 64];
  const int t = threadIdx.x;
  const int wave = t >> 6, l = t & 63, lr = l & 15, lg = l >> 4;
  const int bh = blockIdx.y, b = bh >> 4, h = bh & 15;
  const int qt = gridDim.x - 1 - blockIdx.x;  // big blocks first
  const int q0w = qt * 64 + wave * 16;
  const int ntiles = qt + 1;
  const float cexp = 0.18033688011112042f;  // (1/8) * log2(e)

  // Q fragments (loaded once)
  const unsigned short* qbase = qkv + (size_t)(b * TT + q0w + lr) * N3 + h * HSS;
  bf16x8 qf0 = ld8(qbase + lg * 8);
  bf16x8 qf1 = ld8(qbase + 32 + lg * 8);

  // staging source addresses (pre-swizzled): LDS byte o = issue*4096 + t*16
  const int o0 = t * 16, o1 = 4096 + t * 16;
  const int r0 = o0 >> 7, c0 = (o0 & 127) ^ ((r0 & 7) << 4);
  const int r1 = o1 >> 7, c1 = (o1 & 127) ^ ((r1 & 7) << 4);
  const char* gK0 = (const char*)(qkv + (size_t)(b * TT + r0) * N3 + CC + h * HSS) + c0;
  const char* gK1 = (const char*)(qkv + (size_t)(b * TT + r1) * N3 + CC + h * HSS) + c1;
  const char* gV0 = (const char*)(vt + ((size_t)bh * HSS + r0) * TT) + c0;
  const char* gV1 = (const char*)(vt + ((size_t)bh * HSS + r1) * TT) + c1;

#define STAGE(buf_, it_)                                                  \
  do {                                                                    \
    size_t kb = (size_t)(it_) * (64 * N3 * 2);                            \
    size_t vb = (size_t)(it_) * 128;                                      \
    glds16(gK0 + kb, (char*)Ks[buf_] + wave * 1024);                      \
    glds16(gK1 + kb, (char*)Ks[buf_] + 4096 + wave * 1024);               \
    glds16(gV0 + vb, (char*)Vs[buf_] + wave * 1024);                      \
    glds16(gV1 + vb, (char*)Vs[buf_] + 4096 + wave * 1024);               \
  } while (0)

  float m_s = -INFINITY, l_s = 0.f;
  f32x4 o[4] = {};
  const int swl = (lr & 7) << 4;
  char* prow = (char*)Ps[wave] + lr * 128;

  STAGE(0, 0);
  for (int it = 0; it < ntiles; ++it) {
    if (it + 1 < ntiles) {
      STAGE((it + 1) & 1, it + 1);
      __builtin_amdgcn_sched_barrier(0);
      asm volatile("s_waitcnt vmcnt(4)" ::: "memory");
    } else {
      asm volatile("s_waitcnt vmcnt(0)" ::: "memory");
    }
    __builtin_amdgcn_s_barrier();
    __builtin_amdgcn_sched_barrier(0);

    const unsigned short* Kb = Ks[it & 1];
    const unsigned short* Vb = Vs[it & 1];
    const int kv0 = it * 64;

    // QK^T (swapped): s[sk] holds S^T[kv=sk*16+4*lg+j][q=lr]
    f32x4 s[4];
#pragma unroll
    for (int sk = 0; sk < 4; sk++) {
      const char* kr = (const char*)Kb + (sk * 16 + lr) * 128;
      bf16x8 kf0 = ld8((const unsigned short*)(kr + ((lg * 16) ^ swl)));
      bf16x8 kf1 = ld8((const unsigned short*)(kr + ((64 + lg * 16) ^ swl)));
      f32x4 z = {0.f, 0.f, 0.f, 0.f};
      z = mfma16(kf0, qf0, z);
      s[sk] = mfma16(kf1, qf1, z);
    }

    // causal mask only needed on the last tile
    if (it == ntiles - 1) {
      const int q = q0w + lr;
#pragma unroll
      for (int sk = 0; sk < 4; sk++)
#pragma unroll
        for (int j = 0; j < 4; j++) {
          int kv = kv0 + sk * 16 + 4 * lg + j;
          if (kv > q) s[sk][j] = -INFINITY;
        }
    }

    // online softmax (per lane: q = lr)
    float tmax = -INFINITY;
#pragma unroll
    for (int sk = 0; sk < 4; sk++)
#pragma unroll
      for (int j = 0; j < 4; j++) tmax = fmaxf(tmax, s[sk][j]);
    tmax = fmaxf(tmax, __shfl_xor(tmax, 16));
    tmax = fmaxf(tmax, __shfl_xor(tmax, 32));
    float m_new = fmaxf(m_s, tmax);
    float alpha = __builtin_amdgcn_exp2f((m_s - m_new) * cexp);
    float tsum = 0.f;
    float p[16];
#pragma unroll
    for (int sk = 0; sk < 4; sk++)
#pragma unroll
      for (int j = 0; j < 4; j++) {
        float pv = __builtin_amdgcn_exp2f((s[sk][j] - m_new) * cexp);
        p[sk * 4 + j] = pv;
        tsum += pv;
      }
    tsum += __shfl_xor(tsum, 16);
    tsum += __shfl_xor(tsum, 32);
    m_s = m_new;
    l_s = l_s * alpha + tsum;

    // P -> LDS (swizzled rows, 2-way max on banks), wave-local bounce
#pragma unroll
    for (int sk = 0; sk < 4; sk++) {
      ushort4 w;
      w.x = f2bf(p[sk * 4 + 0]); w.y = f2bf(p[sk * 4 + 1]);
      w.z = f2bf(p[sk * 4 + 2]); w.w = f2bf(p[sk * 4 + 3]);
      *(ushort4*)(prow + ((sk * 32 + lg * 8) ^ swl)) = w;
    }
    asm volatile("s_waitcnt lgkmcnt(0)" ::: "memory");
    __builtin_amdgcn_sched_barrier(0);
    bf16x8 pa0 = ld8((const unsigned short*)(prow + ((lg * 16) ^ swl)));
    bf16x8 pa1 = ld8((const unsigned short*)(prow + ((64 + lg * 16) ^ swl)));

    // PV: o accumulator rows q=4*lg+j (C layout), rescale then accumulate
    float ar[4];
#pragma unroll
    for (int j = 0; j < 4; j++) ar[j] = __shfl(alpha, 4 * lg + j);
#pragma unroll
    for (int nt = 0; nt < 4; nt++) {
      const char* vr = (const char*)Vb + (nt * 16 + lr) * 128;
#pragma unroll
      for (int j = 0; j < 4; j++) o[nt][j] *= ar[j];
      bf16x8 vf0 = ld8((const unsigned short*)(vr + ((lg * 16) ^ swl)));
      bf16x8 vf1 = ld8((const unsigned short*)(vr + ((64 + lg * 16) ^ swl)));
      o[nt] = mfma16(pa0, vf0, o[nt]);
      o[nt] = mfma16(pa1, vf1, o[nt]);
    }
    __builtin_amdgcn_s_barrier();
    __builtin_amdgcn_sched_barrier(0);
  }
#undef STAGE

  float lrow[4];
#pragma unroll
  for (int j = 0; j < 4; j++) lrow[j] = __shfl(l_s, 4 * lg + j);
  unsigned short* yrow = y + (size_t)(b * TT + q0w + 4 * lg) * CC + h * HSS + lr;
#pragma unroll
  for (int nt = 0; nt < 4; nt++)
#pragma unroll
    for (int j = 0; j < 4; j++)
      yrow[(size_t)j * CC + nt * 16] = f2bf(o[nt][j] / lrow[j]);
}

extern "C" void kernel_launch(void* const* d_in, const int* in_sizes, int n_in,
                              void* d_out, int out_size, void* d_ws, size_t ws_size,
                              hipStream_t stream) {
  const float* x = (const float*)d_in[0];
  const float* b_attn = (const float*)d_in[2];
  const float* b_proj = (const float*)d_in[4];
  const float* W_attn = (const float*)d_in[1];
  const float* W_proj = (const float*)d_in[3];

  char* ws = (char*)d_ws;
  unsigned short* xb   = (unsigned short*)(ws);                       // 8 MB
  unsigned short* wabt = (unsigned short*)(ws + 8388608);             // 6 MB  [3072][1024]
  unsigned short* wpbt = (unsigned short*)(ws + 14680064);            // 2 MB  [1024][1024]
  unsigned short* qkvb = (unsigned short*)(ws + 16777216);            // 24 MB [4096][3072]
  unsigned short* vt   = (unsigned short*)(ws + 41943040);            // 8 MB  [32][64][2048]
  unsigned short* yb   = (unsigned short*)(ws + 50331648);            // 8 MB  [4096][1024]

  k_conv<<<2048, 256, 0, stream>>>(x, xb, BT * CC / 4);
  k_transp<<<dim3(N3 / 32, CC / 32), dim3(32, 8), 0, stream>>>(W_attn, wabt, CC, N3);
  k_transp<<<dim3(CC / 32, CC / 32), dim3(32, 8), 0, stream>>>(W_proj, wpbt, CC, CC);
  k_gemm<1><<<dim3(N3 / 128, BT / 128), 256, 0, stream>>>(xb, wabt, b_attn, qkvb, BT, N3, CC);
  k_vt<<<dim3(TT / 64, BB * NHH), dim3(64, 4), 0, stream>>>(qkvb, vt);
  k_attn<<<dim3(TT / 64, BB * NHH), 256, 0, stream>>>(qkvb, vt, yb);
  k_gemm<0><<<dim3(CC / 128, BT / 128), 256, 0, stream>>>(yb, wpbt, b_proj, d_out, BT, CC, CC);
}

// Round 3
// 135.099 us; speedup vs baseline: 2.3277x; 1.2060x over previous
//
#include <hip/hip_runtime.h>
#include <hip/hip_bf16.h>
#include <stdint.h>

#define DEV static __device__ __forceinline__

typedef __attribute__((ext_vector_type(8))) __bf16 bf16x8;
typedef __attribute__((ext_vector_type(4))) __bf16 bf16x4;
typedef __attribute__((ext_vector_type(4))) float f32x4;

// B=2, T=2048, C=1024, NH=16, HS=64
#define BB 2
#define TT 2048
#define CC 1024
#define NHH 16
#define HSS 64
#define BT 4096
#define N3 3072

DEV unsigned short f2bf(float f) {
  union { float f; uint32_t u; } v; v.f = f;
  uint32_t r = v.u + 0x7FFFu + ((v.u >> 16) & 1u);
  return (unsigned short)(r >> 16);
}

typedef const __attribute__((address_space(1))) unsigned int* gas_t;
typedef __attribute__((address_space(3))) unsigned int* las_t;

DEV void glds16(const void* g, void* l) {
  __builtin_amdgcn_global_load_lds((gas_t)g, (las_t)l, 16, 0, 0);
}

DEV f32x4 mfma16(bf16x8 a, bf16x8 b, f32x4 c) {
  return __builtin_amdgcn_mfma_f32_16x16x32_bf16(a, b, c, 0, 0, 0);
}

DEV bf16x8 ld8(const unsigned short* p) { return *(const bf16x8*)p; }

// ---------- fp32 -> bf16 convert (vectorized) ----------
__global__ void k_conv(const float* __restrict__ in, unsigned short* __restrict__ out, int n4) {
  int i = blockIdx.x * blockDim.x + threadIdx.x;
  int stride = gridDim.x * blockDim.x;
  for (; i < n4; i += stride) {
    float4 v = ((const float4*)in)[i];
    ushort4 o;
    o.x = f2bf(v.x); o.y = f2bf(v.y); o.z = f2bf(v.z); o.w = f2bf(v.w);
    ((ushort4*)out)[i] = o;
  }
}

// ---------- transpose+convert: in [K][N] f32 -> out [N][K] bf16 ----------
__global__ void k_transp(const float* __restrict__ in, unsigned short* __restrict__ out,
                         int K, int N) {
  __shared__ float tile[32][33];
  int n0 = blockIdx.x * 32, k0 = blockIdx.y * 32;
  int tx = threadIdx.x, ty = threadIdx.y;  // (32,8)
  for (int r = ty; r < 32; r += 8)
    tile[r][tx] = in[(size_t)(k0 + r) * N + n0 + tx];
  __syncthreads();
  for (int r = ty; r < 32; r += 8)
    out[(size_t)(n0 + r) * K + k0 + tx] = f2bf(tile[tx][r]);
}

// ---------- m97-structure GEMM: A[M][K] bf16, Bt[N][K] bf16, bias f32[N] ----------
template <int OUT_BF16>
__global__ __launch_bounds__(256) void k_gemm(const unsigned short* __restrict__ A,
                                              const unsigned short* __restrict__ Bt,
                                              const float* __restrict__ bias,
                                              void* __restrict__ Cout,
                                              int M, int N, int K) {
  __shared__ __align__(16) unsigned short As[128 * 32];
  __shared__ __align__(16) unsigned short Bs[128 * 32];
  const int t = threadIdx.x;
  const int wave = t >> 6, l = t & 63, lr = l & 15, lg = l >> 4;
  const int m0 = blockIdx.y * 128, n0 = blockIdx.x * 128;
  const int wm = wave >> 1, wn = wave & 1;

  f32x4 acc[4][4] = {};

  const unsigned short* gA = A + (size_t)(m0 + (t >> 2)) * K + (t & 3) * 8;
  const unsigned short* gB = Bt + (size_t)(n0 + (t >> 2)) * K + (t & 3) * 8;
  char* lA = (char*)As + wave * 1024;
  char* lB = (char*)Bs + wave * 1024;
  const size_t rstep = (size_t)64 * K;

  for (int k0 = 0; k0 < K; k0 += 32) {
    glds16(gA + k0, lA);
    glds16(gA + rstep + k0, lA + 4096);
    glds16(gB + k0, lB);
    glds16(gB + rstep + k0, lB + 4096);
    __syncthreads();
    bf16x8 av[4], bv[4];
#pragma unroll
    for (int i = 0; i < 4; i++) {
      av[i] = ld8(As + (wm * 64 + i * 16 + lr) * 32 + lg * 8);
      bv[i] = ld8(Bs + (wn * 64 + i * 16 + lr) * 32 + lg * 8);
    }
#pragma unroll
    for (int i = 0; i < 4; i++)
#pragma unroll
      for (int j = 0; j < 4; j++)
        acc[i][j] = mfma16(av[i], bv[j], acc[i][j]);
    __syncthreads();
  }

#pragma unroll
  for (int j2 = 0; j2 < 4; j2++) {
    int col = n0 + wn * 64 + j2 * 16 + lr;
    float bv_ = bias[col];
#pragma unroll
    for (int i = 0; i < 4; i++) {
      int row = m0 + wm * 64 + i * 16 + lg * 4;
#pragma unroll
      for (int r = 0; r < 4; r++) {
        float v = acc[i][j2][r] + bv_;
        if (OUT_BF16)
          ((unsigned short*)Cout)[(size_t)(row + r) * N + col] = f2bf(v);
        else
          ((float*)Cout)[(size_t)(row + r) * N + col] = v;
      }
    }
  }
}

// ---------- per-head V transpose: qkv[b][t][2048+h*64+d] -> vt[bh][d][t] ----------
__global__ void k_vt(const unsigned short* __restrict__ qkv, unsigned short* __restrict__ vt) {
  __shared__ unsigned short tile[64][65];
  int bh = blockIdx.y, t0 = blockIdx.x * 64;
  int b = bh >> 4, h = bh & 15;
  int tx = threadIdx.x, ty = threadIdx.y;  // (64,4)
  const unsigned short* src = qkv + (size_t)(b * TT + t0) * N3 + 2 * CC + h * HSS;
  __syncthreads();
  for (int r = ty; r < 64; r += 4)
    tile[r][tx] = src[(size_t)r * N3 + tx];
  __syncthreads();
  unsigned short* dst = vt + (size_t)bh * HSS * TT + t0;
  for (int r = ty; r < 64; r += 4)
    dst[(size_t)r * TT + tx] = tile[tx][r];
}

// ---------- flash attention: paired q-tiles, 4-deep K/V ring, defer-max ----------
// Block = 4 waves, handles q-tile (31-p) then q-tile p -> exactly 33 kv tiles.
// One s_barrier per tile; counted vmcnt; rescale only when running max grows.
__global__ __launch_bounds__(256) void k_attn(const unsigned short* __restrict__ qkv,
                                              const unsigned short* __restrict__ vt,
                                              unsigned short* __restrict__ y) {
  __shared__ __align__(16) unsigned short Ks[4][64 * 64];
  __shared__ __align__(16) unsigned short Vs[4][64 * 64];
  __shared__ __align__(16) unsigned short Ps[4][16 * 64];
  const int t = threadIdx.x;
  const int wave = t >> 6, l = t & 63, lr = l & 15, lg = l >> 4;
  const int bh = blockIdx.y, b = bh >> 4, h = bh & 15;
  const int p = blockIdx.x;            // 0..15
  const int qtA = 31 - p, qtB = p;
  const int ntA = qtA + 1;             // tiles in segment A; total = 33
  const float cexp = 0.18033688011112042f;  // (1/8) * log2(e)
  const float THR = 40.0f;                  // raw-units defer threshold (~exp2(7.2) bound)

  // staging source addresses (pre-swizzled): LDS byte o = issue*4096 + t*16
  const int o0 = t * 16, o1 = 4096 + t * 16;
  const int r0 = o0 >> 7, c0 = (o0 & 127) ^ ((r0 & 7) << 4);
  const int r1 = o1 >> 7, c1 = (o1 & 127) ^ ((r1 & 7) << 4);
  const char* gK0 = (const char*)(qkv + (size_t)(b * TT + r0) * N3 + CC + h * HSS) + c0;
  const char* gK1 = (const char*)(qkv + (size_t)(b * TT + r1) * N3 + CC + h * HSS) + c1;
  const char* gV0 = (const char*)(vt + ((size_t)bh * HSS + r0) * TT) + c0;
  const char* gV1 = (const char*)(vt + ((size_t)bh * HSS + r1) * TT) + c1;

#define STAGE(buf_, seq_)                                                 \
  do {                                                                    \
    int kvt_ = ((seq_) < ntA) ? (seq_) : ((seq_) - ntA);                  \
    size_t kb = (size_t)kvt_ * (64 * N3 * 2);                             \
    size_t vb = (size_t)kvt_ * 128;                                       \
    glds16(gK0 + kb, (char*)Ks[buf_] + wave * 1024);                      \
    glds16(gK1 + kb, (char*)Ks[buf_] + 4096 + wave * 1024);               \
    glds16(gV0 + vb, (char*)Vs[buf_] + wave * 1024);                      \
    glds16(gV1 + vb, (char*)Vs[buf_] + 4096 + wave * 1024);               \
  } while (0)

  const int swl = (lr & 7) << 4;
  char* prow = (char*)Ps[wave] + lr * 128;

  // segment state
  int q0w = qtA * 64 + wave * 16;
  const unsigned short* qb = qkv + (size_t)(b * TT + q0w + lr) * N3 + h * HSS;
  bf16x8 qf0 = ld8(qb + lg * 8);
  bf16x8 qf1 = ld8(qb + 32 + lg * 8);
  float m_s = -INFINITY, l_ln = 0.f;
  f32x4 o[4] = {};

  STAGE(0, 0);
  STAGE(1, 1);

  for (int seq = 0; seq < 33; ++seq) {
    if (seq == ntA) {
      // finalize segment A
      {
        float l_q = l_ln + __shfl_xor(l_ln, 16);
        l_q += __shfl_xor(l_q, 32);
        float lrow[4];
#pragma unroll
        for (int j = 0; j < 4; j++) lrow[j] = __shfl(l_q, 4 * lg + j);
        unsigned short* yrow = y + (size_t)(b * TT + q0w + 4 * lg) * CC + h * HSS + lr;
#pragma unroll
        for (int nt = 0; nt < 4; nt++)
#pragma unroll
          for (int j = 0; j < 4; j++)
            yrow[(size_t)j * CC + nt * 16] = f2bf(o[nt][j] / lrow[j]);
      }
      // reset for segment B
      q0w = qtB * 64 + wave * 16;
      const unsigned short* qb2 = qkv + (size_t)(b * TT + q0w + lr) * N3 + h * HSS;
      qf0 = ld8(qb2 + lg * 8);
      qf1 = ld8(qb2 + 32 + lg * 8);
      m_s = -INFINITY; l_ln = 0.f;
#pragma unroll
      for (int nt = 0; nt < 4; nt++) o[nt] = f32x4{0.f, 0.f, 0.f, 0.f};
    }

    if (seq + 2 < 33) {
      STAGE((seq + 2) & 3, seq + 2);
      __builtin_amdgcn_sched_barrier(0);
      asm volatile("s_waitcnt vmcnt(8)" ::: "memory");
    } else if (seq + 1 < 33) {
      asm volatile("s_waitcnt vmcnt(4)" ::: "memory");
    } else {
      asm volatile("s_waitcnt vmcnt(0)" ::: "memory");
    }
    __builtin_amdgcn_s_barrier();
    __builtin_amdgcn_sched_barrier(0);

    const unsigned short* Kb = Ks[seq & 3];
    const unsigned short* Vb = Vs[seq & 3];
    const int kvt = (seq < ntA) ? seq : (seq - ntA);
    const int kv0 = kvt * 64;
    const bool lastTile = (seq == qtA) || (seq == 32);

    // QK^T (swapped): s[sk] holds S^T[kv=kv0+sk*16+4*lg+j][q=q0w+lr]
    f32x4 s[4];
    __builtin_amdgcn_s_setprio(1);
#pragma unroll
    for (int sk = 0; sk < 4; sk++) {
      const char* kr = (const char*)Kb + (sk * 16 + lr) * 128;
      bf16x8 kf0 = ld8((const unsigned short*)(kr + ((lg * 16) ^ swl)));
      bf16x8 kf1 = ld8((const unsigned short*)(kr + ((64 + lg * 16) ^ swl)));
      f32x4 z = {0.f, 0.f, 0.f, 0.f};
      z = mfma16(kf0, qf0, z);
      s[sk] = mfma16(kf1, qf1, z);
    }
    __builtin_amdgcn_s_setprio(0);

    if (lastTile) {
      const int q = q0w + lr;
#pragma unroll
      for (int sk = 0; sk < 4; sk++)
#pragma unroll
        for (int j = 0; j < 4; j++) {
          int kv = kv0 + sk * 16 + 4 * lg + j;
          if (kv > q) s[sk][j] = -INFINITY;
        }
    }

    // per-lane max (tree)
    float a0 = fmaxf(fmaxf(s[0][0], s[0][1]), fmaxf(s[0][2], s[0][3]));
    float a1 = fmaxf(fmaxf(s[1][0], s[1][1]), fmaxf(s[1][2], s[1][3]));
    float a2 = fmaxf(fmaxf(s[2][0], s[2][1]), fmaxf(s[2][2], s[2][3]));
    float a3 = fmaxf(fmaxf(s[3][0], s[3][1]), fmaxf(s[3][2], s[3][3]));
    float tmax = fmaxf(fmaxf(a0, a1), fmaxf(a2, a3));

    if (!__all(tmax <= m_s + THR)) {
      // rescale path (rare): full cross-lane max for this q-row
      float tm = fmaxf(tmax, __shfl_xor(tmax, 16));
      tm = fmaxf(tm, __shfl_xor(tm, 32));
      float m_new = fmaxf(m_s, tm);
      float alpha = __builtin_amdgcn_exp2f((m_s - m_new) * cexp);
      l_ln *= alpha;
      float ar[4];
#pragma unroll
      for (int j = 0; j < 4; j++) ar[j] = __shfl(alpha, 4 * lg + j);
#pragma unroll
      for (int nt = 0; nt < 4; nt++)
#pragma unroll
        for (int j = 0; j < 4; j++) o[nt][j] *= ar[j];
      m_s = m_new;
    }

    const float mc = m_s * cexp;
    float tsum = 0.f;
    bf16x4 pw[4];
#pragma unroll
    for (int sk = 0; sk < 4; sk++) {
#pragma unroll
      for (int j = 0; j < 4; j++) {
        float pv = __builtin_amdgcn_exp2f(__builtin_fmaf(s[sk][j], cexp, -mc));
        tsum += pv;
        pw[sk][j] = (__bf16)pv;
      }
    }
    l_ln += tsum;

    // P -> LDS (swizzled rows), wave-local bounce
#pragma unroll
    for (int sk = 0; sk < 4; sk++)
      *(bf16x4*)(prow + ((sk * 32 + lg * 8) ^ swl)) = pw[sk];
    asm volatile("s_waitcnt lgkmcnt(0)" ::: "memory");
    __builtin_amdgcn_sched_barrier(0);
    bf16x8 pa0 = ld8((const unsigned short*)(prow + ((lg * 16) ^ swl)));
    bf16x8 pa1 = ld8((const unsigned short*)(prow + ((64 + lg * 16) ^ swl)));

    // PV: o rows q=4*lg+j
    __builtin_amdgcn_s_setprio(1);
#pragma unroll
    for (int nt = 0; nt < 4; nt++) {
      const char* vr = (const char*)Vb + (nt * 16 + lr) * 128;
      bf16x8 vf0 = ld8((const unsigned short*)(vr + ((lg * 16) ^ swl)));
      bf16x8 vf1 = ld8((const unsigned short*)(vr + ((64 + lg * 16) ^ swl)));
      o[nt] = mfma16(pa0, vf0, o[nt]);
      o[nt] = mfma16(pa1, vf1, o[nt]);
    }
    __builtin_amdgcn_s_setprio(0);
  }
#undef STAGE

  // finalize segment B
  float l_q = l_ln + __shfl_xor(l_ln, 16);
  l_q += __shfl_xor(l_q, 32);
  float lrow[4];
#pragma unroll
  for (int j = 0; j < 4; j++) lrow[j] = __shfl(l_q, 4 * lg + j);
  unsigned short* yrow = y + (size_t)(b * TT + q0w + 4 * lg) * CC + h * HSS + lr;
#pragma unroll
  for (int nt = 0; nt < 4; nt++)
#pragma unroll
    for (int j = 0; j < 4; j++)
      yrow[(size_t)j * CC + nt * 16] = f2bf(o[nt][j] / lrow[j]);
}

extern "C" void kernel_launch(void* const* d_in, const int* in_sizes, int n_in,
                              void* d_out, int out_size, void* d_ws, size_t ws_size,
                              hipStream_t stream) {
  const float* x = (const float*)d_in[0];
  const float* W_attn = (const float*)d_in[1];
  const float* b_attn = (const float*)d_in[2];
  const float* W_proj = (const float*)d_in[3];
  const float* b_proj = (const float*)d_in[4];

  char* ws = (char*)d_ws;
  unsigned short* xb   = (unsigned short*)(ws);                       // 8 MB
  unsigned short* wabt = (unsigned short*)(ws + 8388608);             // 6 MB  [3072][1024]
  unsigned short* wpbt = (unsigned short*)(ws + 14680064);            // 2 MB  [1024][1024]
  unsigned short* qkvb = (unsigned short*)(ws + 16777216);            // 24 MB [4096][3072]
  unsigned short* vt   = (unsigned short*)(ws + 41943040);            // 8 MB  [32][64][2048]
  unsigned short* yb   = (unsigned short*)(ws + 50331648);            // 8 MB  [4096][1024]

  k_conv<<<2048, 256, 0, stream>>>(x, xb, BT * CC / 4);
  k_transp<<<dim3(N3 / 32, CC / 32), dim3(32, 8), 0, stream>>>(W_attn, wabt, CC, N3);
  k_transp<<<dim3(CC / 32, CC / 32), dim3(32, 8), 0, stream>>>(W_proj, wpbt, CC, CC);
  k_gemm<1><<<dim3(N3 / 128, BT / 128), 256, 0, stream>>>(xb, wabt, b_attn, qkvb, BT, N3, CC);
  k_vt<<<dim3(TT / 64, BB * NHH), dim3(64, 4), 0, stream>>>(qkvb, vt);
  k_attn<<<dim3(16, BB * NHH), 256, 0, stream>>>(qkvb, vt, yb);
  k_gemm<0><<<dim3(CC / 128, BT / 128), 256, 0, stream>>>(yb, wpbt, b_proj, d_out, BT, CC, CC);
}